// Round 5
// baseline (472.571 us; speedup 1.0000x reference)
//
#include <hip/hip_runtime.h>
#include <cstdint>
#include <cstddef>

typedef unsigned short u16;
typedef unsigned int u32;

typedef __bf16 bf16x8 __attribute__((ext_vector_type(8)));
typedef float f32x4 __attribute__((ext_vector_type(4)));
typedef u32 u32x4 __attribute__((ext_vector_type(4)));
typedef u32 u32x2 __attribute__((ext_vector_type(2)));

#if defined(__has_builtin)
#if __has_builtin(__builtin_amdgcn_global_load_lds)
#define USE_GLL 1
#endif
#endif

typedef const __attribute__((address_space(1))) u32 gas_u32;
typedef __attribute__((address_space(3))) u32 las_u32;

__device__ inline float bf2f(u16 u) {
    union { u32 i; float f; } c; c.i = ((u32)u) << 16; return c.f;
}
__device__ inline u16 f2bf(float f) {
    union { float f; u32 i; } c; c.f = f;
    u32 u = c.i;
    return (u16)((u + 0x7fffu + ((u >> 16) & 1u)) >> 16);  // RNE
}
// packed f32x2 -> bf16x2 (RNE; bit-identical to f2bf pair, 1 VALU instr)
__device__ inline u32 cvtpk(float lo, float hi) {
    u32 r; asm("v_cvt_pk_bf16_f32 %0, %1, %2" : "=v"(r) : "v"(lo), "v"(hi)); return r;
}
__device__ inline f32x4 mfma16(u32x4 a, u32x4 b, f32x4 c) {
    return __builtin_amdgcn_mfma_f32_16x16x32_bf16(
        __builtin_bit_cast(bf16x8, a), __builtin_bit_cast(bf16x8, b), c, 0, 0, 0);
}
__device__ inline u32x4 cvt8(const float* p) {
    f32x4 a = *(const f32x4*)p, b = *(const f32x4*)(p + 4);
    u32x4 v;
    v[0] = (u32)f2bf(a[0]) | ((u32)f2bf(a[1]) << 16);
    v[1] = (u32)f2bf(a[2]) | ((u32)f2bf(a[3]) << 16);
    v[2] = (u32)f2bf(b[0]) | ((u32)f2bf(b[1]) << 16);
    v[3] = (u32)f2bf(b[2]) | ((u32)f2bf(b[3]) << 16);
    return v;
}

// LDS-only barrier: orders LDS traffic, leaves global ops in flight.
__device__ inline void bar_lds() {
    asm volatile("s_waitcnt lgkmcnt(0)" ::: "memory");
    __builtin_amdgcn_s_barrier();
    __builtin_amdgcn_sched_barrier(0);
}

// ===================== dtype detector (round-1 forensics: inputs fp32) ========
__global__ __launch_bounds__(64) void k_detect(const u16* __restrict__ x, u32* __restrict__ flag)
{
    const int lane = threadIdx.x;
    int cnt = 0;
#pragma unroll
    for (int i = 0; i < 4; i++) {
        u32 e = (x[lane * 4 + i] >> 7) & 0xFF;
        cnt += (e >= 115 && e <= 133) ? 1 : 0;
    }
#pragma unroll
    for (int off = 1; off < 64; off <<= 1) cnt += __shfl_xor(cnt, off);
    if (lane == 0) *flag = (cnt >= 192) ? 1u : 0u;
}

// ===================== X -> bf16 convert (one-shot; copy if already bf16) =====
__global__ __launch_bounds__(256) void k_convert_x(
    const void* __restrict__ X, u16* __restrict__ xb, const u32* __restrict__ flag)
{
    const bool isb = (*flag != 0);
    const size_t i = ((size_t)blockIdx.x * 256 + threadIdx.x) * 8;
    if (isb) *(u32x4*)(xb + i) = *(const u32x4*)((const u16*)X + i);
    else     *(u32x4*)(xb + i) = cvt8((const float*)X + i);
}

// ===================== weight transpose (unchanged, validated) ================
__global__ __launch_bounds__(256) void k_transpose_w(
    const void* __restrict__ Wq, const void* __restrict__ Wkv, const void* __restrict__ Wo,
    u16* __restrict__ WT, u16* __restrict__ WoT, const u32* __restrict__ flag)
{
    const bool isb = (*flag != 0);
    __shared__ __align__(16) u16 t[64][72];
    const int z = blockIdx.z;
    const void* src; u16* dst; int C;
    if (z == 0)      { src = Wq;  dst = WT;             C = 768;  }
    else if (z == 1) { src = Wkv; dst = WT + 768 * 768; C = 1536; }
    else             { src = Wo;  dst = WoT;            C = 768;  }
    const int c0 = blockIdx.y * 64;
    if (c0 >= C) return;
    const int k0 = blockIdx.x * 64;
    const int tid = threadIdx.x;
    const int r = tid >> 3, cc = (tid & 7) * 8;
    if (isb) {
        const u16* s = (const u16*)src;
        for (int rr = r; rr < 64; rr += 32)
            *(u32x4*)&t[rr][cc] = *(const u32x4*)(s + (size_t)(k0 + rr) * C + c0 + cc);
    } else {
        const float* s = (const float*)src;
        for (int rr = r; rr < 64; rr += 32)
            *(u32x4*)&t[rr][cc] = cvt8(s + (size_t)(k0 + rr) * C + c0 + cc);
    }
    __syncthreads();
    const int kk = (tid & 7) * 8;
    for (int ccc = tid >> 3; ccc < 64; ccc += 32) {
        __align__(16) u16 tmp[8];
#pragma unroll
        for (int s = 0; s < 8; s++) tmp[s] = t[kk + s][ccc];
        *(u32x4*)(dst + (size_t)(c0 + ccc) * 768 + k0 + kk) = *(u32x4*)tmp;
    }
}

// ===================== v transpose (unchanged, validated) =====================
__global__ __launch_bounds__(256) void k_transpose_v(
    const u16* __restrict__ v, u16* __restrict__ vt)
{
    __shared__ __align__(16) u16 t[64][72];
    const int bh = blockIdx.z;
    const int t0 = blockIdx.x * 64;
    const int tid = threadIdx.x;
    const int r = tid >> 3, cc = (tid & 7) * 8;
    for (int rr = r; rr < 64; rr += 32)
        *(u32x4*)&t[rr][cc] = *(const u32x4*)(v + ((size_t)bh * 1024 + t0 + rr) * 64 + cc);
    __syncthreads();
    const int kk = (tid & 7) * 8;
    for (int ccc = tid >> 3; ccc < 64; ccc += 32) {
        __align__(16) u16 tmp[8];
#pragma unroll
        for (int s = 0; s < 8; s++) tmp[s] = t[kk + s][ccc];
        *(u32x4*)(vt + ((size_t)bh * 64 + ccc) * 1024 + t0 + kk) = *(u32x4*)tmp;
    }
}

// ---- shared staging helper for the 128x128 m97-style GEMMs -------------------
__device__ inline void stage_tile(const u16* __restrict__ gA, const u16* __restrict__ gB,
                                  u16* As, u16* Bs, int w, int lane)
{
    const int sr = lane >> 2, sc = (lane & 3) * 8;
#pragma unroll
    for (int i = 0; i < 2; i++) {
        const int rA = w * 16 + i * 64;
        const u16* ga = gA + (size_t)(rA + sr) * 768 + sc;
        const u16* gb = gB + (size_t)(rA + sr) * 768 + sc;
#ifdef USE_GLL
        __builtin_amdgcn_global_load_lds((gas_u32*)ga, (las_u32*)&As[rA * 32], 16, 0, 0);
        __builtin_amdgcn_global_load_lds((gas_u32*)gb, (las_u32*)&Bs[rA * 32], 16, 0, 0);
#else
        *(u32x4*)&As[(rA + sr) * 32 + sc] = *(const u32x4*)ga;
        *(u32x4*)&Bs[(rA + sr) * 32 + sc] = *(const u32x4*)gb;
#endif
    }
}

// ===================== QKV GEMM v2: 128x128 tile, global_load_lds =============
__global__ __launch_bounds__(256) void k_gemm_qkv(
    const u16* __restrict__ Xb, const u16* __restrict__ WT,
    u16* __restrict__ qb, u16* __restrict__ kb, u16* __restrict__ vb)
{
    __shared__ __align__(16) u16 As[128 * 32];
    __shared__ __align__(16) u16 Bs[128 * 32];
    const int tid = threadIdx.x;
    const int w = tid >> 6, lane = tid & 63, quad = lane >> 4, l15 = lane & 15;
    const int wr = w >> 1, wc = w & 1;
    const int m0 = blockIdx.y * 128, c0 = blockIdx.x * 128;
    f32x4 acc[4][4];
#pragma unroll
    for (int i = 0; i < 4; i++)
#pragma unroll
        for (int j = 0; j < 4; j++) acc[i][j] = (f32x4){0.f, 0.f, 0.f, 0.f};

    for (int k0 = 0; k0 < 768; k0 += 32) {
        __syncthreads();
        stage_tile(Xb + (size_t)m0 * 768 + k0, WT + (size_t)c0 * 768 + k0, As, Bs, w, lane);
        __syncthreads();
        u32x4 af[4], bfv[4];
#pragma unroll
        for (int mi = 0; mi < 4; mi++)
            af[mi] = *(const u32x4*)&As[(wr * 64 + mi * 16 + l15) * 32 + quad * 8];
#pragma unroll
        for (int ni = 0; ni < 4; ni++)
            bfv[ni] = *(const u32x4*)&Bs[(wc * 64 + ni * 16 + l15) * 32 + quad * 8];
#pragma unroll
        for (int mi = 0; mi < 4; mi++)
#pragma unroll
            for (int ni = 0; ni < 4; ni++)
                acc[mi][ni] = mfma16(af[mi], bfv[ni], acc[mi][ni]);
    }
#pragma unroll
    for (int mi = 0; mi < 4; mi++)
#pragma unroll
        for (int ni = 0; ni < 4; ni++) {
            const int c = c0 + wc * 64 + ni * 16 + l15;
            const int sector = c / 768, hc = c % 768;
            const int h = hc >> 6, d = hc & 63;
            u16* dst = sector == 0 ? qb : (sector == 1 ? kb : vb);
#pragma unroll
            for (int r = 0; r < 4; r++) {
                const int tok = m0 + wr * 64 + mi * 16 + quad * 4 + r;
                const int b = tok >> 10, n = tok & 1023;
                dst[(((size_t)b * 12 + h) * 1024 + n) * 64 + d] = f2bf(acc[mi][ni][r]);
            }
        }
}

// ===================== output GEMM v2: 128x128 tile, fp32 out ================
__global__ __launch_bounds__(256) void k_gemm_out(
    const u16* __restrict__ O, const u16* __restrict__ WoT, const void* __restrict__ bo,
    float* __restrict__ out, const u32* __restrict__ flag)
{
    const bool isb = (*flag != 0);
    __shared__ __align__(16) u16 As[128 * 32];
    __shared__ __align__(16) u16 Bs[128 * 32];
    const int tid = threadIdx.x;
    const int w = tid >> 6, lane = tid & 63, quad = lane >> 4, l15 = lane & 15;
    const int wr = w >> 1, wc = w & 1;
    const int m0 = blockIdx.y * 128, c0 = blockIdx.x * 128;
    f32x4 acc[4][4];
#pragma unroll
    for (int i = 0; i < 4; i++)
#pragma unroll
        for (int j = 0; j < 4; j++) acc[i][j] = (f32x4){0.f, 0.f, 0.f, 0.f};

    for (int k0 = 0; k0 < 768; k0 += 32) {
        __syncthreads();
        stage_tile(O + (size_t)m0 * 768 + k0, WoT + (size_t)c0 * 768 + k0, As, Bs, w, lane);
        __syncthreads();
        u32x4 af[4], bfv[4];
#pragma unroll
        for (int mi = 0; mi < 4; mi++)
            af[mi] = *(const u32x4*)&As[(wr * 64 + mi * 16 + l15) * 32 + quad * 8];
#pragma unroll
        for (int ni = 0; ni < 4; ni++)
            bfv[ni] = *(const u32x4*)&Bs[(wc * 64 + ni * 16 + l15) * 32 + quad * 8];
#pragma unroll
        for (int mi = 0; mi < 4; mi++)
#pragma unroll
            for (int ni = 0; ni < 4; ni++)
                acc[mi][ni] = mfma16(af[mi], bfv[ni], acc[mi][ni]);
    }
#pragma unroll
    for (int mi = 0; mi < 4; mi++)
#pragma unroll
        for (int ni = 0; ni < 4; ni++) {
            const int c = c0 + wc * 64 + ni * 16 + l15;
            const float biasv = isb ? bf2f(((const u16*)bo)[c]) : ((const float*)bo)[c];
#pragma unroll
            for (int r = 0; r < 4; r++) {
                const int tok = m0 + wr * 64 + mi * 16 + quad * 4 + r;
                out[(size_t)tok * 768 + c] = acc[mi][ni][r] + biasv;
            }
        }
}

// ---- E-slab staging (16 waves): 24,576 B slab = 16x1KB + 8x1KB chunks --------
__device__ inline void stage_e(const u16* __restrict__ src, u16* dst, int w, int lane)
{
    const int o1 = (w * 64 + lane) * 8;
#ifdef USE_GLL
    __builtin_amdgcn_global_load_lds((gas_u32*)(src + o1), (las_u32*)(dst + o1), 16, 0, 0);
#else
    *(u32x4*)(dst + o1) = *(const u32x4*)(src + o1);
#endif
    if (w < 8) {
        const int o2 = ((16 + w) * 64 + lane) * 8;
#ifdef USE_GLL
        __builtin_amdgcn_global_load_lds((gas_u32*)(src + o2), (las_u32*)(dst + o2), 16, 0, 0);
#else
        *(u32x4*)(dst + o2) = *(const u32x4*)(src + o2);
#endif
    }
}

// =====================================================================
// k_attn v8.1: 16-wave restructure (v8 + compile fix: no LDS pointer
// ARRAY initializer -- backend rejects addrspacecast in static init;
// Abuf base computed inline per iteration instead).
//   * 1024 threads = 16 waves = 4/SIMD; phases divide evenly:
//     QK/PV 48 slots = 3/wave, premix/am 64 slots = 4/wave.
//   * SP and Abuf double-buffered (LDS union) -> 1 barrier per jt per
//     pass.  Barrier crossings per tile: 64 -> 34.
//   * E layout store-coalesced: [jt][s][qg(3)][l15(16)][4 heads];
//     pass-1 store = 384 contiguous B/instr.  Pass-2 read remapped.
//   * E-slab staging issue-early / vmcnt(0)-before-barrier.
//   * v_cvt_pk_bf16_f32 for E pack (RNE, bit-identical, -VALU).
//   LDS: SPdbuf 73,728 + invl 1,024 + Eslab 49,152 = 123,904 B (1 WG).
// =====================================================================
__global__ __launch_bounds__(1024) void k_attn(
    const u16* __restrict__ qb, const u16* __restrict__ kb, const u16* __restrict__ vt,
    const void* __restrict__ mixpre, const void* __restrict__ mixpost,
    u16* __restrict__ ob, u16* __restrict__ E, const u32* __restrict__ flag, int tiles)
{
    __shared__ __align__(16) u16 SPd[2][1024 * 18];   // 73,728 B; pass-2 unions Abuf dbuf
    __shared__ float invlT[256];                      // [i][h] 16x16 f32
    __shared__ __align__(16) u16 Eslab[2][12288];     // 49,152 B pass-2 E slabs
    float* red = (float*)&Eslab[0][0];                // 4 KB reduction scratch (pass-boundary only)

    const bool isb = (*flag != 0);
    const int tid = threadIdx.x;
    const int w = tid >> 6, lane = tid & 63, quad = lane >> 4, l15 = lane & 15;
    const int nt = w & 3, h0 = w >> 2;                // wave's n-tile and head base
    const int bid = blockIdx.x;
    const int b = bid & 7;                            // XCD-aware: batch per XCD
    const int nq = gridDim.x >> 3;
    u16* Ewg = E + (size_t)bid * (16384 * 12);

    u32x4 apre = (u32x4){0, 0, 0, 0};
    float mpostF[8];
#pragma unroll
    for (int j = 0; j < 8; j++) {
        const int h = quad * 8 + j;
        mpostF[j] = 0.f;
        if (quad < 2 && l15 < 12 && h < 12) {
            mpostF[j] = isb ? bf2f(((const u16*)mixpost)[h * 12 + l15])
                            : ((const float*)mixpost)[h * 12 + l15];
            u16 v1 = isb ? ((const u16*)mixpre)[h * 12 + l15]
                         : f2bf(((const float*)mixpre)[h * 12 + l15]);
            apre[j >> 1] |= ((u32)v1) << ((j & 1) * 16);
        }
    }

    for (int tt = 0; tt < tiles; tt++) {
        const int qx = (bid >> 3) + tt * nq;
        const int i0 = qx * 16;

        bar_lds();   // protect prev tile's Abuf/SP reads before re-zero (T=2 path)
        {            // zero SP cols 12-15 of BOTH buffers (premix b-frag padding)
            u32* spz = (u32*)&SPd[0][0];
            for (int n = tid; n < 2048; n += 1024) { spz[n * 9 + 6] = 0; spz[n * 9 + 7] = 0; }
        }

        // Q fragments for this wave's 3 heads
        u32x4 aq[3][2];
#pragma unroll
        for (int t = 0; t < 3; t++) {
            const u16* qh = qb + (((size_t)b * 12 + (h0 + 4 * t)) * 1024 + i0) * 64;
#pragma unroll
            for (int kc = 0; kc < 2; kc++)
                aq[t][kc] = *(const u32x4*)(qh + l15 * 64 + kc * 32 + quad * 8);
        }

        // ---------------- pass 1: QK^T -> premix -> exp -> E + row sums ------
        f32x4 part[4];
#pragma unroll
        for (int t = 0; t < 4; t++) part[t] = (f32x4){0.f, 0.f, 0.f, 0.f};

        for (int jt = 0; jt < 16; jt++) {
            u16* SPc = &SPd[0][0] + (jt & 1) * (1024 * 18);
            u32* SPc32 = (u32*)SPc;
            const int j0 = jt * 64;
            // QK: 3 slots (h0+4t, nt)
#pragma unroll
            for (int t = 0; t < 3; t++) {
                const int h = h0 + 4 * t;
                const u16* khp = kb + ((size_t)b * 12 + h) * 65536;
                f32x4 a = (f32x4){0.f, 0.f, 0.f, 0.f};
#pragma unroll
                for (int kc = 0; kc < 2; kc++) {
                    u32x4 bfr = *(const u32x4*)(khp + (size_t)(j0 + nt * 16 + l15) * 64 + kc * 32 + quad * 8);
                    a = mfma16(aq[t][kc], bfr, a);
                }
#pragma unroll
                for (int r = 0; r < 4; r++)
                    SPc[((quad * 4 + r) * 64 + nt * 16 + l15) * 18 + h] = f2bf(a[r] * 0.125f);
            }
            bar_lds();                         // SP[cur] writes visible (dbuf: 1 bar/jt)
            // premix: 4 slots (s = w + 16t)
#pragma unroll
            for (int t = 0; t < 4; t++) {
                const int s = w + 16 * t;
                const int row = s * 16 + l15;
                u32x4 bfr = (u32x4){0, 0, 0, 0};
                if (quad < 2) {
                    const u32* p = SPc32 + row * 9 + quad * 4;
                    bfr[0] = p[0]; bfr[1] = p[1]; bfr[2] = p[2]; bfr[3] = p[3];
                }
                f32x4 d = mfma16(apre, bfr, (f32x4){0.f, 0.f, 0.f, 0.f});
                const float e0 = __expf(d[0]), e1 = __expf(d[1]);
                const float e2 = __expf(d[2]), e3 = __expf(d[3]);
                part[t][0] += e0; part[t][1] += e1;
                part[t][2] += e2; part[t][3] += e3;
                if (quad < 3) {                // heads quad*4 .. quad*4+3, coalesced
                    u32x2 pk;
                    pk[0] = cvtpk(e0, e1);
                    pk[1] = cvtpk(e2, e3);
                    *(u32x2*)(Ewg + ((size_t)(jt * 64 + s) * 3 + quad) * 64 + l15 * 4) = pk;
                }
            }
        }
        __syncthreads();   // FULL drain: E-stores retired; SP reads done

        // row-sum finalize (red lives in Eslab[0] area; dead before staging)
#pragma unroll
        for (int t = 0; t < 4; t++) {
            const int s = w + 16 * t;
#pragma unroll
            for (int r = 0; r < 4; r++) {
                float v = part[t][r];
#pragma unroll
                for (int off = 1; off < 16; off <<= 1) v += __shfl_xor(v, off);
                if (l15 == 0) red[(((s >> 2) * 16) + quad * 4 + r) * 4 + (s & 3)] = v;
            }
        }
        bar_lds();
        if (tid < 256) {
            const int h = tid & 15;
            float v = 0.f;
            if (h < 12) {
                const float* q = &red[tid * 4];
                v = 1.f / (q[0] + q[1] + q[2] + q[3]);
            }
            invlT[tid] = v;
        }
        bar_lds();

        u32x4 Afr[4];
#pragma unroll
        for (int t = 0; t < 4; t++) {
            const int s = w + 16 * t;
            const int i = s >> 2;
            Afr[t] = (u32x4){0, 0, 0, 0};
            if (quad < 2) {
#pragma unroll
                for (int j = 0; j < 8; j++) {
                    const int h = quad * 8 + j;
                    if (h < 12) {
                        const u16 v = f2bf(mpostF[j] * invlT[i * 16 + h]);
                        Afr[t][j >> 1] |= ((u32)v) << ((j & 1) * 16);
                    }
                }
            }
        }
        stage_e(Ewg, Eslab[0], w, lane);       // prologue slab (red already consumed)
        __syncthreads();                       // drains staging; slab 0 visible

        // ---------------- pass 2: E slab -> postmix -> PV --------------------
        f32x4 oacc[3];
#pragma unroll
        for (int t = 0; t < 3; t++) oacc[t] = (f32x4){0.f, 0.f, 0.f, 0.f};

        for (int jt = 0; jt < 16; jt++) {
            const int cur = jt & 1;
            u16* Ab = &SPd[0][0] + cur * 13920;   // 27,840 B halves within SP union
            const int j0 = jt * 64;
            if (jt < 15)
                stage_e(Ewg + (size_t)(jt + 1) * 12288, Eslab[cur ^ 1], w, lane);
            // am: 4 slots (s = w + 16t)
#pragma unroll
            for (int t = 0; t < 4; t++) {
                const int s = w + 16 * t;
                const int i = s >> 2, jq = s & 3;
                u32x4 ef = (u32x4){0, 0, 0, 0};
                if (quad < 2) {
                    const u32* sl = (const u32*)&Eslab[cur][0];
                    const int base = (s * 3 + quad * 2) * 32 + l15 * 2;
                    u32x2 lo = *(const u32x2*)(sl + base);
                    ef[0] = lo[0]; ef[1] = lo[1];
                    if (quad == 0) {
                        u32x2 hi = *(const u32x2*)(sl + base + 32);
                        ef[2] = hi[0]; ef[3] = hi[1];
                    }
                }
                f32x4 am = mfma16(Afr[t], ef, (f32x4){0.f, 0.f, 0.f, 0.f});
#pragma unroll
                for (int r = 0; r < 4; r++) {
                    const int g2 = quad * 4 + r;
                    if (g2 < 12)
                        Ab[g2 * 1160 + i * 72 + jq * 16 + l15] = f2bf(am[r]);
                }
            }
            asm volatile("s_waitcnt vmcnt(0)" ::: "memory");  // next slab drained
            bar_lds();                          // Abuf[cur] + next slab visible
            // PV: 3 slots (h0+4t, nt)
#pragma unroll
            for (int t = 0; t < 3; t++) {
                const int h = h0 + 4 * t;
                const u16* vhp = vt + ((size_t)b * 12 + h) * 65536;
#pragma unroll
                for (int kc = 0; kc < 2; kc++) {
                    u32x4 af = *(const u32x4*)&Ab[h * 1160 + l15 * 72 + kc * 32 + quad * 8];
                    u32x4 vf = *(const u32x4*)(vhp + (size_t)(nt * 16 + l15) * 1024 + j0 + kc * 32 + quad * 8);
                    oacc[t] = mfma16(af, vf, oacc[t]);
                }
            }
        }
#pragma unroll
        for (int t = 0; t < 3; t++) {
            const int h = h0 + 4 * t;
#pragma unroll
            for (int r = 0; r < 4; r++)
                ob[((size_t)b * 1024 + i0 + quad * 4 + r) * 768 + h * 64 + nt * 16 + l15] =
                    f2bf(oacc[t][r]);
        }
    }
}

// =====================================================================
extern "C" void kernel_launch(void* const* d_in, const int* in_sizes, int n_in,
                              void* d_out, int out_size, void* d_ws, size_t ws_size,
                              hipStream_t stream)
{
    float* out = (float*)d_out;

    u32* flag = (u32*)d_ws;
    u16* WoT  = (u16*)d_ws + 128;            // 589,824 u16
    u16* qb   = WoT + 768 * 768;             // 6,291,456 each
    u16* kb   = qb  + 6291456;
    u16* vtb  = kb  + 6291456;
    u16* obuf = vtb + 6291456;               // aliases vb (v dead after transpose)
    u16* vb   = obuf;
    u16* ez   = obuf + 6291456;              // E zone; WT+xb alias it (dead before k_attn)
    u16* WT   = ez;                          // 1,769,472 u16
    u16* xb   = ez + 2304 * 768;             // 6,291,456 u16 bf16 X
    u16* E    = ez;

    const size_t base   = 256 + 2ull * (768 * 768 + 4ull * 6291456);   // 51.5 MB
    const size_t eslot  = 16384ull * 12 * 2;                           // 393,216 B per WG
    const size_t need1  = base + 512ull * eslot + 64;                  // ~252.8 MB -> T=1
    const size_t need2  = base + 256ull * eslot + 64;                  // ~152.2 MB -> T=2

    k_detect     <<<dim3(1), 64,  0, stream>>>((const u16*)d_in[0], flag);
    k_transpose_w<<<dim3(12, 24, 3), 256, 0, stream>>>(d_in[1], d_in[2], d_in[5], WT, WoT, flag);
    k_convert_x  <<<dim3(3072),      256, 0, stream>>>(d_in[0], xb, flag);
    k_gemm_qkv   <<<dim3(18, 64),    256, 0, stream>>>(xb, WT, qb, kb, vb);
    k_transpose_v<<<dim3(16, 1, 96), 256, 0, stream>>>(vb, vtb);
    if (ws_size >= need1)
        k_attn   <<<dim3(512), 1024, 0, stream>>>(qb, kb, vtb, d_in[3], d_in[4], obuf, E, flag, 1);
    else
        k_attn   <<<dim3(256), 1024, 0, stream>>>(qb, kb, vtb, d_in[3], d_in[4], obuf, E, flag, 2);
    k_gemm_out   <<<dim3(6, 64),     256, 0, stream>>>(obuf, WoT, d_in[6], out, flag);
}

// Round 6
// 470.282 us; speedup vs baseline: 1.0049x; 1.0049x over previous
//
#include <hip/hip_runtime.h>
#include <cstdint>
#include <cstddef>

typedef unsigned short u16;
typedef unsigned int u32;

typedef __bf16 bf16x8 __attribute__((ext_vector_type(8)));
typedef float f32x4 __attribute__((ext_vector_type(4)));
typedef u32 u32x4 __attribute__((ext_vector_type(4)));
typedef u32 u32x2 __attribute__((ext_vector_type(2)));

#if defined(__has_builtin)
#if __has_builtin(__builtin_amdgcn_global_load_lds)
#define USE_GLL 1
#endif
#endif

typedef const __attribute__((address_space(1))) u32 gas_u32;
typedef __attribute__((address_space(3))) u32 las_u32;

__device__ inline float bf2f(u16 u) {
    union { u32 i; float f; } c; c.i = ((u32)u) << 16; return c.f;
}
__device__ inline u16 f2bf(float f) {
    union { float f; u32 i; } c; c.f = f;
    u32 u = c.i;
    return (u16)((u + 0x7fffu + ((u >> 16) & 1u)) >> 16);  // RNE
}
// packed f32x2 -> bf16x2 (RNE; bit-identical to f2bf pair, 1 VALU instr)
__device__ inline u32 cvtpk(float lo, float hi) {
    u32 r; asm("v_cvt_pk_bf16_f32 %0, %1, %2" : "=v"(r) : "v"(lo), "v"(hi)); return r;
}
__device__ inline f32x4 mfma16(u32x4 a, u32x4 b, f32x4 c) {
    return __builtin_amdgcn_mfma_f32_16x16x32_bf16(
        __builtin_bit_cast(bf16x8, a), __builtin_bit_cast(bf16x8, b), c, 0, 0, 0);
}
__device__ inline u32x4 cvt8(const float* p) {
    f32x4 a = *(const f32x4*)p, b = *(const f32x4*)(p + 4);
    u32x4 v;
    v[0] = (u32)f2bf(a[0]) | ((u32)f2bf(a[1]) << 16);
    v[1] = (u32)f2bf(a[2]) | ((u32)f2bf(a[3]) << 16);
    v[2] = (u32)f2bf(b[0]) | ((u32)f2bf(b[1]) << 16);
    v[3] = (u32)f2bf(b[2]) | ((u32)f2bf(b[3]) << 16);
    return v;
}

// LDS-only barrier: orders LDS traffic, leaves global ops in flight.
__device__ inline void bar_lds() {
    asm volatile("s_waitcnt lgkmcnt(0)" ::: "memory");
    __builtin_amdgcn_s_barrier();
    __builtin_amdgcn_sched_barrier(0);
}

// ===================== dtype detector (round-1 forensics: inputs fp32) ========
__global__ __launch_bounds__(64) void k_detect(const u16* __restrict__ x, u32* __restrict__ flag)
{
    const int lane = threadIdx.x;
    int cnt = 0;
#pragma unroll
    for (int i = 0; i < 4; i++) {
        u32 e = (x[lane * 4 + i] >> 7) & 0xFF;
        cnt += (e >= 115 && e <= 133) ? 1 : 0;
    }
#pragma unroll
    for (int off = 1; off < 64; off <<= 1) cnt += __shfl_xor(cnt, off);
    if (lane == 0) *flag = (cnt >= 192) ? 1u : 0u;
}

// ===================== X -> bf16 convert (one-shot; copy if already bf16) =====
__global__ __launch_bounds__(256) void k_convert_x(
    const void* __restrict__ X, u16* __restrict__ xb, const u32* __restrict__ flag)
{
    const bool isb = (*flag != 0);
    const size_t i = ((size_t)blockIdx.x * 256 + threadIdx.x) * 8;
    if (isb) *(u32x4*)(xb + i) = *(const u32x4*)((const u16*)X + i);
    else     *(u32x4*)(xb + i) = cvt8((const float*)X + i);
}

// ===================== weight transpose (unchanged, validated) ================
__global__ __launch_bounds__(256) void k_transpose_w(
    const void* __restrict__ Wq, const void* __restrict__ Wkv, const void* __restrict__ Wo,
    u16* __restrict__ WT, u16* __restrict__ WoT, const u32* __restrict__ flag)
{
    const bool isb = (*flag != 0);
    __shared__ __align__(16) u16 t[64][72];
    const int z = blockIdx.z;
    const void* src; u16* dst; int C;
    if (z == 0)      { src = Wq;  dst = WT;             C = 768;  }
    else if (z == 1) { src = Wkv; dst = WT + 768 * 768; C = 1536; }
    else             { src = Wo;  dst = WoT;            C = 768;  }
    const int c0 = blockIdx.y * 64;
    if (c0 >= C) return;
    const int k0 = blockIdx.x * 64;
    const int tid = threadIdx.x;
    const int r = tid >> 3, cc = (tid & 7) * 8;
    if (isb) {
        const u16* s = (const u16*)src;
        for (int rr = r; rr < 64; rr += 32)
            *(u32x4*)&t[rr][cc] = *(const u32x4*)(s + (size_t)(k0 + rr) * C + c0 + cc);
    } else {
        const float* s = (const float*)src;
        for (int rr = r; rr < 64; rr += 32)
            *(u32x4*)&t[rr][cc] = cvt8(s + (size_t)(k0 + rr) * C + c0 + cc);
    }
    __syncthreads();
    const int kk = (tid & 7) * 8;
    for (int ccc = tid >> 3; ccc < 64; ccc += 32) {
        __align__(16) u16 tmp[8];
#pragma unroll
        for (int s = 0; s < 8; s++) tmp[s] = t[kk + s][ccc];
        *(u32x4*)(dst + (size_t)(c0 + ccc) * 768 + k0 + kk) = *(u32x4*)tmp;
    }
}

// ===================== v transpose (unchanged, validated) =====================
__global__ __launch_bounds__(256) void k_transpose_v(
    const u16* __restrict__ v, u16* __restrict__ vt)
{
    __shared__ __align__(16) u16 t[64][72];
    const int bh = blockIdx.z;
    const int t0 = blockIdx.x * 64;
    const int tid = threadIdx.x;
    const int r = tid >> 3, cc = (tid & 7) * 8;
    for (int rr = r; rr < 64; rr += 32)
        *(u32x4*)&t[rr][cc] = *(const u32x4*)(v + ((size_t)bh * 1024 + t0 + rr) * 64 + cc);
    __syncthreads();
    const int kk = (tid & 7) * 8;
    for (int ccc = tid >> 3; ccc < 64; ccc += 32) {
        __align__(16) u16 tmp[8];
#pragma unroll
        for (int s = 0; s < 8; s++) tmp[s] = t[kk + s][ccc];
        *(u32x4*)(vt + ((size_t)bh * 64 + ccc) * 1024 + t0 + kk) = *(u32x4*)tmp;
    }
}

// ---- shared staging helper for the 128x128 m97-style GEMMs -------------------
__device__ inline void stage_tile(const u16* __restrict__ gA, const u16* __restrict__ gB,
                                  u16* As, u16* Bs, int w, int lane)
{
    const int sr = lane >> 2, sc = (lane & 3) * 8;
#pragma unroll
    for (int i = 0; i < 2; i++) {
        const int rA = w * 16 + i * 64;
        const u16* ga = gA + (size_t)(rA + sr) * 768 + sc;
        const u16* gb = gB + (size_t)(rA + sr) * 768 + sc;
#ifdef USE_GLL
        __builtin_amdgcn_global_load_lds((gas_u32*)ga, (las_u32*)&As[rA * 32], 16, 0, 0);
        __builtin_amdgcn_global_load_lds((gas_u32*)gb, (las_u32*)&Bs[rA * 32], 16, 0, 0);
#else
        *(u32x4*)&As[(rA + sr) * 32 + sc] = *(const u32x4*)ga;
        *(u32x4*)&Bs[(rA + sr) * 32 + sc] = *(const u32x4*)gb;
#endif
    }
}

// ===================== QKV GEMM v2: 128x128 tile, global_load_lds =============
__global__ __launch_bounds__(256) void k_gemm_qkv(
    const u16* __restrict__ Xb, const u16* __restrict__ WT,
    u16* __restrict__ qb, u16* __restrict__ kb, u16* __restrict__ vb)
{
    __shared__ __align__(16) u16 As[128 * 32];
    __shared__ __align__(16) u16 Bs[128 * 32];
    const int tid = threadIdx.x;
    const int w = tid >> 6, lane = tid & 63, quad = lane >> 4, l15 = lane & 15;
    const int wr = w >> 1, wc = w & 1;
    const int m0 = blockIdx.y * 128, c0 = blockIdx.x * 128;
    f32x4 acc[4][4];
#pragma unroll
    for (int i = 0; i < 4; i++)
#pragma unroll
        for (int j = 0; j < 4; j++) acc[i][j] = (f32x4){0.f, 0.f, 0.f, 0.f};

    for (int k0 = 0; k0 < 768; k0 += 32) {
        __syncthreads();
        stage_tile(Xb + (size_t)m0 * 768 + k0, WT + (size_t)c0 * 768 + k0, As, Bs, w, lane);
        __syncthreads();
        u32x4 af[4], bfv[4];
#pragma unroll
        for (int mi = 0; mi < 4; mi++)
            af[mi] = *(const u32x4*)&As[(wr * 64 + mi * 16 + l15) * 32 + quad * 8];
#pragma unroll
        for (int ni = 0; ni < 4; ni++)
            bfv[ni] = *(const u32x4*)&Bs[(wc * 64 + ni * 16 + l15) * 32 + quad * 8];
#pragma unroll
        for (int mi = 0; mi < 4; mi++)
#pragma unroll
            for (int ni = 0; ni < 4; ni++)
                acc[mi][ni] = mfma16(af[mi], bfv[ni], acc[mi][ni]);
    }
#pragma unroll
    for (int mi = 0; mi < 4; mi++)
#pragma unroll
        for (int ni = 0; ni < 4; ni++) {
            const int c = c0 + wc * 64 + ni * 16 + l15;
            const int sector = c / 768, hc = c % 768;
            const int h = hc >> 6, d = hc & 63;
            u16* dst = sector == 0 ? qb : (sector == 1 ? kb : vb);
#pragma unroll
            for (int r = 0; r < 4; r++) {
                const int tok = m0 + wr * 64 + mi * 16 + quad * 4 + r;
                const int b = tok >> 10, n = tok & 1023;
                dst[(((size_t)b * 12 + h) * 1024 + n) * 64 + d] = f2bf(acc[mi][ni][r]);
            }
        }
}

// ===================== output GEMM v2: 128x128 tile, fp32 out ================
__global__ __launch_bounds__(256) void k_gemm_out(
    const u16* __restrict__ O, const u16* __restrict__ WoT, const void* __restrict__ bo,
    float* __restrict__ out, const u32* __restrict__ flag)
{
    const bool isb = (*flag != 0);
    __shared__ __align__(16) u16 As[128 * 32];
    __shared__ __align__(16) u16 Bs[128 * 32];
    const int tid = threadIdx.x;
    const int w = tid >> 6, lane = tid & 63, quad = lane >> 4, l15 = lane & 15;
    const int wr = w >> 1, wc = w & 1;
    const int m0 = blockIdx.y * 128, c0 = blockIdx.x * 128;
    f32x4 acc[4][4];
#pragma unroll
    for (int i = 0; i < 4; i++)
#pragma unroll
        for (int j = 0; j < 4; j++) acc[i][j] = (f32x4){0.f, 0.f, 0.f, 0.f};

    for (int k0 = 0; k0 < 768; k0 += 32) {
        __syncthreads();
        stage_tile(O + (size_t)m0 * 768 + k0, WoT + (size_t)c0 * 768 + k0, As, Bs, w, lane);
        __syncthreads();
        u32x4 af[4], bfv[4];
#pragma unroll
        for (int mi = 0; mi < 4; mi++)
            af[mi] = *(const u32x4*)&As[(wr * 64 + mi * 16 + l15) * 32 + quad * 8];
#pragma unroll
        for (int ni = 0; ni < 4; ni++)
            bfv[ni] = *(const u32x4*)&Bs[(wc * 64 + ni * 16 + l15) * 32 + quad * 8];
#pragma unroll
        for (int mi = 0; mi < 4; mi++)
#pragma unroll
            for (int ni = 0; ni < 4; ni++)
                acc[mi][ni] = mfma16(af[mi], bfv[ni], acc[mi][ni]);
    }
#pragma unroll
    for (int mi = 0; mi < 4; mi++)
#pragma unroll
        for (int ni = 0; ni < 4; ni++) {
            const int c = c0 + wc * 64 + ni * 16 + l15;
            const float biasv = isb ? bf2f(((const u16*)bo)[c]) : ((const float*)bo)[c];
#pragma unroll
            for (int r = 0; r < 4; r++) {
                const int tok = m0 + wr * 64 + mi * 16 + quad * 4 + r;
                out[(size_t)tok * 768 + c] = acc[mi][ni][r] + biasv;
            }
        }
}

// ---- E-slab staging: one jt-slab (24,576 B) via 12 waves x 2 chunks ----------
__device__ inline void stage_e(const u16* __restrict__ src, u16* dst, int w, int lane)
{
#pragma unroll
    for (int c = 0; c < 2; c++) {
        const int off = ((w * 2 + c) * 64 + lane) * 8;
#ifdef USE_GLL
        __builtin_amdgcn_global_load_lds((gas_u32*)(src + off), (las_u32*)(dst + off), 16, 0, 0);
#else
        *(u32x4*)(dst + off) = *(const u32x4*)(src + off);
#endif
    }
}

// =====================================================================
// k_attn v9: v7 (round-3 validated, 291us, 84 VGPR, no spills) + jt-SKEW
// pipelining.  Rounds 1/2/5 proved occupancy>1WG and 16-wave variants
// spill; v9 keeps v7's 12-wave slotting, layouts, registers EXACTLY and
// only re-phases the work:
//   pass 1: phase(jt) = { QK(jt+1) -> SP[(jt+1)&1]  ||  premix(jt) from
//     SP[jt&1] + exp + E-store }; 1 bar/jt (17 vs 32).  K-load latency
//     hides under premix VALU; SP double-buffered (disjoint buffers per
//     phase; barrier flips).
//   pass 2: phase(jt) = { vmcnt(0) [drains slab staged LAST phase],
//     stage_e(jt+2) -> Eslab[jt&1]  ||  am(jt+1) -> Abuf[(jt+1)&1]  ||
//     PV(jt) from Abuf[jt&1] }; 1 bar/jt.  Eslab prefetch 2-deep; the
//     top-of-phase vmcnt(0) is ~free (stage had a full phase in flight)
//     and rigorous against the compiler sinking the gll issue.
//   Abuf[k] lives in SPd[k] (27,840 <= 36,864 B); red in SPd[0] (dead).
//   LDS: 73,728 + 1,024 + 49,184 = 123,936 B (1 WG/CU -- the validated
//   spill-free regime).
// =====================================================================
__global__ __launch_bounds__(768) void k_attn(
    const u16* __restrict__ qb, const u16* __restrict__ kb, const u16* __restrict__ vt,
    const void* __restrict__ mixpre, const void* __restrict__ mixpost,
    u16* __restrict__ ob, u16* __restrict__ E, const u32* __restrict__ flag, int tiles)
{
    __shared__ __align__(16) u16 SPd[2][18432];    // 73,728 B: SP dbuf (p1) / Abuf dbuf (p2)
    __shared__ float invlT[256];                   // [i][h] 16x16 f32
    __shared__ __align__(16) u16 Eslab[2][12296];  // 49,184 B pass-2 E slabs (+8 pad)
    float* red = (float*)&SPd[0][0];               // reduction scratch (pass boundary only)

    const bool isb = (*flag != 0);
    const int tid = threadIdx.x;
    const int w = tid >> 6, lane = tid & 63, quad = lane >> 4, l15 = lane & 15;
    const int bid = blockIdx.x;
    const int b = bid & 7;                         // XCD-aware: batch per XCD
    const int nq = gridDim.x >> 3;
    u16* Ewg = E + (size_t)bid * (16384 * 12);

    u32x4 apre = (u32x4){0, 0, 0, 0};
    float mpostF[8];
#pragma unroll
    for (int j = 0; j < 8; j++) {
        const int h = quad * 8 + j;
        mpostF[j] = 0.f;
        if (quad < 2 && l15 < 12 && h < 12) {
            mpostF[j] = isb ? bf2f(((const u16*)mixpost)[h * 12 + l15])
                            : ((const float*)mixpost)[h * 12 + l15];
            u16 v1 = isb ? ((const u16*)mixpre)[h * 12 + l15]
                         : f2bf(((const float*)mixpre)[h * 12 + l15]);
            apre[j >> 1] |= ((u32)v1) << ((j & 1) * 16);
        }
    }

    const u16* kh = kb + ((size_t)b * 12 + w) * 65536;
    const u16* vh = vt + ((size_t)b * 12 + w) * 65536;

    for (int tt = 0; tt < tiles; tt++) {
        const int qx = (bid >> 3) + tt * nq;
        const int i0 = qx * 16;

        {   // zero premix-padding cols (u32 words 6,7) of BOTH SP buffers
            u32* spz = (u32*)&SPd[0][0];
            for (int n = tid; n < 2048; n += 768) { spz[n * 9 + 6] = 0; spz[n * 9 + 7] = 0; }
        }

        const u16* qh = qb + (((size_t)b * 12 + w) * 1024 + i0) * 64;
        u32x4 aq[2];
#pragma unroll
        for (int kc = 0; kc < 2; kc++)
            aq[kc] = *(const u32x4*)(qh + l15 * 64 + kc * 32 + quad * 8);

        // ---------------- pass 1 (skewed): QK(jt+1) || premix(jt) ------------
        f32x4 part[6];
#pragma unroll
        for (int t = 0; t < 6; t++) part[t] = (f32x4){0.f, 0.f, 0.f, 0.f};

        {   // prologue: QK(0) -> SP[0]
            u16* SPc = &SPd[0][0];
#pragma unroll
            for (int nt = 0; nt < 4; nt++) {
                f32x4 a = (f32x4){0.f, 0.f, 0.f, 0.f};
#pragma unroll
                for (int kc = 0; kc < 2; kc++) {
                    u32x4 bfr = *(const u32x4*)(kh + (size_t)(nt * 16 + l15) * 64 + kc * 32 + quad * 8);
                    a = mfma16(aq[kc], bfr, a);
                }
#pragma unroll
                for (int r = 0; r < 4; r++)
                    SPc[((quad * 4 + r) * 64 + nt * 16 + l15) * 18 + w] = f2bf(a[r] * 0.125f);
            }
        }
        bar_lds();

        for (int jt = 0; jt < 16; jt++) {
            if (jt < 15) {                          // QK(jt+1) -> SP[(jt+1)&1]
                u16* SPn = &SPd[0][0] + ((jt + 1) & 1) * 18432;
                const int j0n = (jt + 1) * 64;
#pragma unroll
                for (int nt = 0; nt < 4; nt++) {
                    f32x4 a = (f32x4){0.f, 0.f, 0.f, 0.f};
#pragma unroll
                    for (int kc = 0; kc < 2; kc++) {
                        u32x4 bfr = *(const u32x4*)(kh + (size_t)(j0n + nt * 16 + l15) * 64 + kc * 32 + quad * 8);
                        a = mfma16(aq[kc], bfr, a);
                    }
#pragma unroll
                    for (int r = 0; r < 4; r++)
                        SPn[((quad * 4 + r) * 64 + nt * 16 + l15) * 18 + w] = f2bf(a[r] * 0.125f);
                }
            }
            // premix(jt) from SP[jt&1]
            const u32* SPc32 = (const u32*)(&SPd[0][0] + (jt & 1) * 18432);
#pragma unroll
            for (int t = 0; t < 6; t++) {
                const int s = w + 12 * t;
                if (s < 64) {
                    const int row = s * 16 + l15;
                    u32x4 bfr = (u32x4){0, 0, 0, 0};
                    if (quad < 2) {
                        const u32* p = SPc32 + row * 9 + quad * 4;
                        bfr[0] = p[0]; bfr[1] = p[1]; bfr[2] = p[2]; bfr[3] = p[3];
                    }
                    f32x4 d = mfma16(apre, bfr, (f32x4){0.f, 0.f, 0.f, 0.f});
                    const float e0 = __expf(d[0]), e1 = __expf(d[1]);
                    const float e2 = __expf(d[2]), e3 = __expf(d[3]);
                    part[t][0] += e0; part[t][1] += e1;
                    part[t][2] += e2; part[t][3] += e3;
                    if (quad < 3) {
                        u32x2 pk;
                        pk[0] = cvtpk(e0, e1);
                        pk[1] = cvtpk(e2, e3);
                        *(u32x2*)(Ewg + ((size_t)jt * 1024 + row) * 12 + quad * 4) = pk;
                    }
                }
            }
            bar_lds();                              // SP[(jt+1)&1] visible; SP[jt&1] reads done
        }
        __syncthreads();   // FULL drain: all E-stores retired before pass 2

        // row-sum finalize (red in SPd[0]; SP dead)
#pragma unroll
        for (int t = 0; t < 6; t++) {
            const int s = w + 12 * t;
            if (s < 64) {
#pragma unroll
                for (int r = 0; r < 4; r++) {
                    float v = part[t][r];
#pragma unroll
                    for (int off = 1; off < 16; off <<= 1) v += __shfl_xor(v, off);
                    if (l15 == 0) red[(((s >> 2) * 16) + quad * 4 + r) * 4 + (s & 3)] = v;
                }
            }
        }
        bar_lds();
        if (tid < 256) {
            const int h = tid & 15;
            float v = 0.f;
            if (h < 12) {
                const float* q = &red[tid * 4];
                v = 1.f / (q[0] + q[1] + q[2] + q[3]);
            }
            invlT[tid] = v;
        }
        bar_lds();

        u32x4 Afr[6];
#pragma unroll
        for (int t = 0; t < 6; t++) {
            const int s = w + 12 * t;
            Afr[t] = (u32x4){0, 0, 0, 0};
            if (s < 64 && quad < 2) {
                const int i = s >> 2;
#pragma unroll
                for (int j = 0; j < 8; j++) {
                    const u16 v = f2bf(mpostF[j] * invlT[i * 16 + quad * 8 + j]);
                    Afr[t][j >> 1] |= ((u32)v) << ((j & 1) * 16);
                }
            }
        }
        // prologue: stage slabs 0 and 1, drain, then am(0) -> Abuf[0]
        stage_e(Ewg, &Eslab[0][0], w, lane);
        stage_e(Ewg + 12288, &Eslab[1][0], w, lane);
        asm volatile("s_waitcnt vmcnt(0)" ::: "memory");
        __builtin_amdgcn_sched_barrier(0);
        bar_lds();                                  // both slabs visible to all waves

        {   // am(0)
            u16* Ab = &SPd[0][0];
#pragma unroll
            for (int t = 0; t < 6; t++) {
                const int s = w + 12 * t;
                if (s < 64) {
                    const int row = s * 16 + l15, i = s >> 2, jq = s & 3;
                    u32x4 ef = (u32x4){0, 0, 0, 0};
                    if (quad < 2) {
                        const u16* ep = &Eslab[0][row * 12 + quad * 8];
                        u32x2 lo = *(const u32x2*)ep;
                        u32x2 hi = *(const u32x2*)(ep + 4);
                        ef[0] = lo[0]; ef[1] = lo[1]; ef[2] = hi[0]; ef[3] = hi[1];
                    }
                    f32x4 am = mfma16(Afr[t], ef, (f32x4){0.f, 0.f, 0.f, 0.f});
#pragma unroll
                    for (int r = 0; r < 4; r++) {
                        const int g2 = quad * 4 + r;
                        if (g2 < 12)
                            Ab[g2 * 1160 + i * 72 + jq * 16 + l15] = f2bf(am[r]);
                    }
                }
            }
        }
        bar_lds();                                  // Abuf[0] visible

        // ---------------- pass 2 (skewed): stage(jt+2) || am(jt+1) || PV(jt) --
        f32x4 oacc[4];
#pragma unroll
        for (int nt = 0; nt < 4; nt++) oacc[nt] = (f32x4){0.f, 0.f, 0.f, 0.f};

        for (int jt = 0; jt < 16; jt++) {
            // drain the slab staged LAST phase (had a full phase in flight)
            asm volatile("s_waitcnt vmcnt(0)" ::: "memory");
            __builtin_amdgcn_sched_barrier(0);
            if (jt < 14)
                stage_e(Ewg + (size_t)(jt + 2) * 12288, &Eslab[jt & 1][0], w, lane);
            if (jt < 15) {                          // am(jt+1) -> Abuf[(jt+1)&1]
                const int nb = (jt + 1) & 1;
                u16* Ab = &SPd[0][0] + nb * 18432;
#pragma unroll
                for (int t = 0; t < 6; t++) {
                    const int s = w + 12 * t;
                    if (s < 64) {
                        const int row = s * 16 + l15, i = s >> 2, jq = s & 3;
                        u32x4 ef = (u32x4){0, 0, 0, 0};
                        if (quad < 2) {
                            const u16* ep = &Eslab[nb][row * 12 + quad * 8];
                            u32x2 lo = *(const u32x2*)ep;
                            u32x2 hi = *(const u32x2*)(ep + 4);
                            ef[0] = lo[0]; ef[1] = lo[1]; ef[2] = hi[0]; ef[3] = hi[1];
                        }
                        f32x4 am = mfma16(Afr[t], ef, (f32x4){0.f, 0.f, 0.f, 0.f});
#pragma unroll
                        for (int r = 0; r < 4; r++) {
                            const int g2 = quad * 4 + r;
                            if (g2 < 12)
                                Ab[g2 * 1160 + i * 72 + jq * 16 + l15] = f2bf(am[r]);
                        }
                    }
                }
            }
            // PV(jt) from Abuf[jt&1]
            {
                const u16* Ab = &SPd[0][0] + (jt & 1) * 18432;
                const int j0 = jt * 64;
#pragma unroll
                for (int kc = 0; kc < 2; kc++) {
                    u32x4 af = *(const u32x4*)&Ab[w * 1160 + l15 * 72 + kc * 32 + quad * 8];
#pragma unroll
                    for (int nt = 0; nt < 4; nt++) {
                        u32x4 vf = *(const u32x4*)(vh + (size_t)(nt * 16 + l15) * 1024 + j0 + kc * 32 + quad * 8);
                        oacc[nt] = mfma16(af, vf, oacc[nt]);
                    }
                }
            }
            bar_lds();                              // Abuf[(jt+1)&1] visible; Abuf[jt&1]/Eslab reads done
        }
#pragma unroll
        for (int nt = 0; nt < 4; nt++)
#pragma unroll
            for (int r = 0; r < 4; r++)
                ob[((size_t)b * 1024 + i0 + quad * 4 + r) * 768 + w * 64 + nt * 16 + l15] =
                    f2bf(oacc[nt][r]);
    }
}

// =====================================================================
extern "C" void kernel_launch(void* const* d_in, const int* in_sizes, int n_in,
                              void* d_out, int out_size, void* d_ws, size_t ws_size,
                              hipStream_t stream)
{
    float* out = (float*)d_out;

    u32* flag = (u32*)d_ws;
    u16* WoT  = (u16*)d_ws + 128;            // 589,824 u16
    u16* qb   = WoT + 768 * 768;             // 6,291,456 each
    u16* kb   = qb  + 6291456;
    u16* vtb  = kb  + 6291456;
    u16* obuf = vtb + 6291456;               // aliases vb (v dead after transpose)
    u16* vb   = obuf;
    u16* ez   = obuf + 6291456;              // E zone; WT+xb alias it (dead before k_attn)
    u16* WT   = ez;                          // 1,769,472 u16
    u16* xb   = ez + 2304 * 768;             // 6,291,456 u16 bf16 X
    u16* E    = ez;

    const size_t base   = 256 + 2ull * (768 * 768 + 4ull * 6291456);   // 51.5 MB
    const size_t eslot  = 16384ull * 12 * 2;                           // 393,216 B per WG
    const size_t need1  = base + 512ull * eslot + 64;                  // ~252.8 MB -> T=1
    const size_t need2  = base + 256ull * eslot + 64;                  // ~152.2 MB -> T=2

    k_detect     <<<dim3(1), 64,  0, stream>>>((const u16*)d_in[0], flag);
    k_transpose_w<<<dim3(12, 24, 3), 256, 0, stream>>>(d_in[1], d_in[2], d_in[5], WT, WoT, flag);
    k_convert_x  <<<dim3(3072),      256, 0, stream>>>(d_in[0], xb, flag);
    k_gemm_qkv   <<<dim3(18, 64),    256, 0, stream>>>(xb, WT, qb, kb, vb);
    k_transpose_v<<<dim3(16, 1, 96), 256, 0, stream>>>(vb, vtb);
    if (ws_size >= need1)
        k_attn   <<<dim3(512), 768, 0, stream>>>(qb, kb, vtb, d_in[3], d_in[4], obuf, E, flag, 1);
    else
        k_attn   <<<dim3(256), 768, 0, stream>>>(qb, kb, vtb, d_in[3], d_in[4], obuf, E, flag, 2);
    k_gemm_out   <<<dim3(6, 64),     256, 0, stream>>>(obuf, WoT, d_in[6], out, flag);
}